// Round 11
// baseline (140.605 us; speedup 1.0000x reference)
//
#include <hip/hip_runtime.h>

// ===== Problem constants =====
// x: [28,14,14,256] -> mean over 7 -> xm[4,196,256]; avgpool2x2 -> xs[4,49,256]
// LAE: qkv = xm @ qkv_w^T [784,768]; per-pixel 3x3 dilated attn (d=1,3) -> y[784,256]
// GAE: q = xm @ lq_w^T [784,128]; kv = xs @ lkv_w^T [196,256]; attn -> ga[784,128]
// proj+cls fused: out[b,cls] = sum_p ((y@Wl^T+bl) . cwl + (ga@Wg^T+bg) . cwg) + cls_b
//
// Structure notes (measured, rounds 1-8):
//  - fixed harness overhead ~93us (268MB d_ws re-poison fill etc.); ~9us per launch
//  - cooperative grid.sync costs ~60us/sync on 400 blocks -> never fuse via coop
//  - fusing the 7-group mean into the GEMM re-reads x 14x => +12us net loss
//  - full unroll of multi-load staging spills to scratch (1.2GB HBM traffic)
//  - this round: 64x64 GEMM tiles, 4x4/thread (8 FMA per LDS b128 read, FMA-bound)

#define WS_XM    0           // 784*256  = 200704
#define WS_XS    200704      // 196*256  = 50176
#define WS_QKV   250880      // 784*768  = 602112
#define WS_QB    852992      // 784*128  = 100352
#define WS_KVB   953344      // 196*256  = 50176
#define WS_Y     1003520     // 784*256  = 200704
#define WS_GA    1204224     // 784*128  = 100352
// total floats = 1304576 (~5.2 MB)

// ---------- kernel 0: group-mean + 2x2 avg pool + out init ----------
// grid 196 = (b, 2x2-quad); 256 threads = 4 pixels x 64 float4-chunks.
__global__ __launch_bounds__(256) void k_mean_pool(const float* __restrict__ x,
                                                   const float* __restrict__ cls_b,
                                                   float* __restrict__ xm,
                                                   float* __restrict__ xs,
                                                   float* __restrict__ out) {
  __shared__ float4 sm[256];
  const int blk = blockIdx.x;
  const int b = blk / 49;
  const int q = blk % 49;
  const int ph2 = q / 7, pw2 = q % 7;
  const int tid = threadIdx.x;
  const int pix = tid >> 6;        // 0..3 -> (dy,dx)
  const int ch4 = (tid & 63) << 2; // float offset 0,4,...,252
  const int p = (ph2 * 2 + (pix >> 1)) * 14 + (pw2 * 2 + (pix & 1));

  const float* xp = x + ((size_t)(b * 1372 + p)) * 256 + ch4;
  float4 v = make_float4(0.f, 0.f, 0.f, 0.f);
  #pragma unroll
  for (int g = 0; g < 7; ++g) {
    const float4 t = *(const float4*)(xp + (size_t)g * 50176);
    v.x += t.x; v.y += t.y; v.z += t.z; v.w += t.w;
  }
  v.x *= (1.f/7.f); v.y *= (1.f/7.f); v.z *= (1.f/7.f); v.w *= (1.f/7.f);
  *(float4*)(xm + (size_t)(b * 196 + p) * 256 + ch4) = v;

  sm[tid] = v;
  __syncthreads();
  if (pix == 0) {
    const int c = tid & 63;
    const float4 v0 = sm[c], v1 = sm[64 + c], v2 = sm[128 + c], v3 = sm[192 + c];
    float4 s;
    s.x = (v0.x + v1.x + v2.x + v3.x) * 0.25f;
    s.y = (v0.y + v1.y + v2.y + v3.y) * 0.25f;
    s.z = (v0.z + v1.z + v2.z + v3.z) * 0.25f;
    s.w = (v0.w + v1.w + v2.w + v3.w) * 0.25f;
    *(float4*)(xs + (size_t)(b * 49 + q) * 256 + ch4) = s;
  }
  if (blk == 0 && tid < 8) out[tid] = cls_b[tid & 1];   // init classifier accumulators
}

// ---------- kernel 1: fused input projections (64x64 tiles, 4x4/thread) ----------
// blocks 0..181:   [qkv|q] = xm @ [qkv_w;lq_w]^T  (M=784, N=896): 13 mt x 14 nt
// blocks 182..197: kv = xs @ lkv_w^T              (M=196, N=256): 4 mt x 4 nt
__global__ __launch_bounds__(256) void k_proj_in(const float* __restrict__ xm,
                                                 const float* __restrict__ xs,
                                                 const float* __restrict__ qkv_w,
                                                 const float* __restrict__ lq_w,
                                                 const float* __restrict__ lkv_w,
                                                 float* __restrict__ qkvb,
                                                 float* __restrict__ qb,
                                                 float* __restrict__ kvb) {
  __shared__ float As[64][68];
  __shared__ float Bs[64][68];
  const int tid = threadIdx.x;
  const int tx = tid & 15, ty = tid >> 4;
  const int bid = blockIdx.x;
  int region, mt, nt;
  if (bid < 182) { region = 0; mt = bid / 14; nt = bid % 14; }
  else { const int r = bid - 182; region = 1; mt = r / 4; nt = r % 4; }
  const float* A = region ? xs : xm;
  const int M = region ? 196 : 784;
  const int rowBase = mt * 64, colBase = nt * 64;

  float acc[4][4];
  #pragma unroll
  for (int i = 0; i < 4; ++i)
    #pragma unroll
    for (int j = 0; j < 4; ++j) acc[i][j] = 0.f;

  for (int kc = 0; kc < 256; kc += 64) {
    #pragma unroll
    for (int i = 0; i < 4; ++i) {           // A tile: 64 rows x 64 k
      const int e = tid + i * 256;
      const int r = e >> 4, k4 = (e & 15) << 2;
      const int row = rowBase + r;
      float4 v = make_float4(0.f, 0.f, 0.f, 0.f);
      if (row < M) v = *(const float4*)(A + (size_t)row * 256 + kc + k4);
      *(float4*)(&As[r][k4]) = v;
    }
    #pragma unroll
    for (int i = 0; i < 4; ++i) {           // B tile: 64 cols x 64 k
      const int e = tid + i * 256;
      const int n = e >> 4, k4 = (e & 15) << 2;
      const int col = colBase + n;
      const float* Wp; int wr;
      if (region == 1)      { Wp = lkv_w; wr = col; }
      else if (col < 768)   { Wp = qkv_w; wr = col; }
      else                  { Wp = lq_w;  wr = col - 768; }
      *(float4*)(&Bs[n][k4]) = *(const float4*)(Wp + (size_t)wr * 256 + kc + k4);
    }
    __syncthreads();
    #pragma unroll
    for (int k = 0; k < 64; k += 4) {
      float4 a[4], c[4];
      #pragma unroll
      for (int i = 0; i < 4; ++i) a[i] = *(const float4*)(&As[ty + 16 * i][k]);
      #pragma unroll
      for (int j = 0; j < 4; ++j) c[j] = *(const float4*)(&Bs[tx + 16 * j][k]);
      #pragma unroll
      for (int i = 0; i < 4; ++i)
        #pragma unroll
        for (int j = 0; j < 4; ++j)
          acc[i][j] += a[i].x*c[j].x + a[i].y*c[j].y + a[i].z*c[j].z + a[i].w*c[j].w;
    }
    __syncthreads();
  }

  #pragma unroll
  for (int j = 0; j < 4; ++j) {
    const int col = colBase + tx + 16 * j;
    #pragma unroll
    for (int i = 0; i < 4; ++i) {
      const int row = rowBase + ty + 16 * i;
      if (row >= M) continue;
      if (region == 1)    kvb[(size_t)row * 256 + col] = acc[i][j];
      else if (col < 768) qkvb[(size_t)row * 768 + col] = acc[i][j];
      else                qb[(size_t)row * 128 + col - 768] = acc[i][j];
    }
  }
}

// ---------- kernel 2: attention (LAE blocks 0..783, GAE blocks 784..799) ----------
__global__ __launch_bounds__(256) void k_attn(const float* __restrict__ qkvb,
                                              const float* __restrict__ qb,
                                              const float* __restrict__ kvb,
                                              float* __restrict__ y,
                                              float* __restrict__ ga) {
  __shared__ float Ks[49 * 32];
  __shared__ float Vs[49 * 32];
  const int bid = blockIdx.x;
  const int tid = threadIdx.x;

  if (bid < 784) {
    // ---- LAE per-pixel dilated 3x3 window attention ----
    const int b = bid / 196, p = bid % 196;
    const int ph = p / 14, pw = p % 14;
    const int c = tid;
    const int d = (c < 128) ? 1 : 3;
    const float qv = qkvb[(size_t)bid * 768 + c];
    float s[9];
    #pragma unroll
    for (int j = 0; j < 9; ++j) {
      const int nh = ph + (j / 3 - 1) * d;
      const int nw = pw + (j % 3 - 1) * d;
      float kval = 0.f;
      if ((unsigned)nh < 14u && (unsigned)nw < 14u)
        kval = qkvb[((size_t)(b * 196 + nh * 14 + nw)) * 768 + 256 + c];
      float t = qv * kval;
      t += __shfl_xor(t, 1);
      t += __shfl_xor(t, 2);
      t += __shfl_xor(t, 4);
      t += __shfl_xor(t, 8);
      t += __shfl_xor(t, 16);
      s[j] = t * 0.17677669529663687f;   // 32^-0.5
    }
    float mx = s[0];
    #pragma unroll
    for (int j = 1; j < 9; ++j) mx = fmaxf(mx, s[j]);
    float sum = 0.f;
    #pragma unroll
    for (int j = 0; j < 9; ++j) { s[j] = __expf(s[j] - mx); sum += s[j]; }
    const float inv = 1.f / sum;
    float o = 0.f;
    #pragma unroll
    for (int j = 0; j < 9; ++j) {
      const int nh = ph + (j / 3 - 1) * d;
      const int nw = pw + (j % 3 - 1) * d;
      if ((unsigned)nh < 14u && (unsigned)nw < 14u)
        o += s[j] * qkvb[((size_t)(b * 196 + nh * 14 + nw)) * 768 + 512 + c];
    }
    y[(size_t)bid * 256 + c] = o * inv;
  } else {
    // ---- GAE attention: 196 queries x 49 keys per (b,head) ----
    const int g = bid - 784;
    const int b = g >> 2, h = g & 3;
    for (int e = tid; e < 49 * 32; e += 256) {
      const int kk = e >> 5, cc = e & 31;
      Ks[e] = kvb[(size_t)(b * 49 + kk) * 256 + h * 32 + cc];
      Vs[e] = kvb[(size_t)(b * 49 + kk) * 256 + 128 + h * 32 + cc];
    }
    __syncthreads();
    if (tid < 196) {
      float q[32], o[32];
      #pragma unroll
      for (int cc = 0; cc < 32; ++cc) {
        q[cc] = qb[(size_t)(b * 196 + tid) * 128 + h * 32 + cc];
        o[cc] = 0.f;
      }
      float m = -1e30f, l = 0.f;
      for (int kk = 0; kk < 49; ++kk) {
        float sc = 0.f;
        #pragma unroll
        for (int cc = 0; cc < 32; ++cc) sc += q[cc] * Ks[kk * 32 + cc];
        sc *= 0.177f;                  // SCALE_GAE (hard-coded in reference)
        if (sc > m) {
          const float r = __expf(m - sc);
          l *= r;
          #pragma unroll
          for (int cc = 0; cc < 32; ++cc) o[cc] *= r;
          m = sc;
        }
        const float pch = __expf(sc - m);
        l += pch;
        #pragma unroll
        for (int cc = 0; cc < 32; ++cc) o[cc] += pch * Vs[kk * 32 + cc];
      }
      const float inv = 1.f / l;
      #pragma unroll
      for (int cc = 0; cc < 32; ++cc)
        ga[(size_t)(b * 196 + tid) * 128 + h * 32 + cc] = o[cc] * inv;
    }
  }
}

// ---------- kernel 3: output projections + classifier (64x64 tiles, 4x4/thread) --
// blocks 0..63:  lae tile = y_b @ lae_proj_w^T + b  (per-b, 4 pt x 4 nt), K=256
// blocks 64..95: gae tile = ga_b @ lproj_w^T + b    (per-b, 4 pt x 2 nt), K=128
__global__ __launch_bounds__(256) void k_proj_cls(const float* __restrict__ y,
                                                  const float* __restrict__ ga,
                                                  const float* __restrict__ lae_w,
                                                  const float* __restrict__ lae_b,
                                                  const float* __restrict__ lproj_w,
                                                  const float* __restrict__ lproj_b,
                                                  const float* __restrict__ cw,
                                                  float* __restrict__ out) {
  __shared__ float As[64][68];
  __shared__ float Bs[64][68];
  const int tid = threadIdx.x;
  const int tx = tid & 15, ty = tid >> 4;
  const int bid = blockIdx.x;
  int region, b, pt, nt;
  if (bid < 64) { region = 0; b = bid / 16; const int r = bid % 16; pt = r / 4; nt = r % 4; }
  else { const int q = bid - 64; region = 1; b = q / 8; const int r = q % 8; pt = r / 2; nt = r % 2; }

  const float* A; const float* W; const float* bias;
  int lda, K, colOff;
  if (region == 0) { A = y  + (size_t)b * 196 * 256; lda = 256; K = 256; W = lae_w;   bias = lae_b;   colOff = 0; }
  else             { A = ga + (size_t)b * 196 * 128; lda = 128; K = 128; W = lproj_w; bias = lproj_b; colOff = 256; }
  const int colBase = nt * 64;

  float acc[4][4];
  #pragma unroll
  for (int i = 0; i < 4; ++i)
    #pragma unroll
    for (int j = 0; j < 4; ++j) acc[i][j] = 0.f;

  for (int kc = 0; kc < K; kc += 64) {
    #pragma unroll
    for (int i = 0; i < 4; ++i) {           // A tile: 64 rows x 64 k
      const int e = tid + i * 256;
      const int r = e >> 4, k4 = (e & 15) << 2;
      const int p = pt * 64 + r;
      float4 v = make_float4(0.f, 0.f, 0.f, 0.f);
      if (p < 196) v = *(const float4*)(A + (size_t)p * lda + kc + k4);
      *(float4*)(&As[r][k4]) = v;
    }
    #pragma unroll
    for (int i = 0; i < 4; ++i) {           // B tile: 64 cols x 64 k
      const int e = tid + i * 256;
      const int n = e >> 4, k4 = (e & 15) << 2;
      const int col = colBase + n;
      *(float4*)(&Bs[n][k4]) = *(const float4*)(W + (size_t)col * K + kc + k4);
    }
    __syncthreads();
    #pragma unroll
    for (int k = 0; k < 64; k += 4) {
      float4 a[4], c[4];
      #pragma unroll
      for (int i = 0; i < 4; ++i) a[i] = *(const float4*)(&As[ty + 16 * i][k]);
      #pragma unroll
      for (int j = 0; j < 4; ++j) c[j] = *(const float4*)(&Bs[tx + 16 * j][k]);
      #pragma unroll
      for (int i = 0; i < 4; ++i)
        #pragma unroll
        for (int j = 0; j < 4; ++j)
          acc[i][j] += a[i].x*c[j].x + a[i].y*c[j].y + a[i].z*c[j].z + a[i].w*c[j].w;
    }
    __syncthreads();
  }

  float s0 = 0.f, s1 = 0.f;
  #pragma unroll
  for (int j = 0; j < 4; ++j) {
    const int col = colBase + tx + 16 * j;
    const float bv = bias[col];
    #pragma unroll
    for (int i = 0; i < 4; ++i) {
      const int p = pt * 64 + ty + 16 * i;
      if (p >= 196) continue;
      const float v = acc[i][j] + bv;
      const size_t fidx = (size_t)p * 384 + colOff + col;
      s0 += v * cw[fidx];
      s1 += v * cw[75264 + fidx];
    }
  }
  float* red = &As[0][0];          // reuse LDS (loop ended with __syncthreads)
  red[tid] = s0;
  red[256 + tid] = s1;
  __syncthreads();
  for (int st = 128; st > 0; st >>= 1) {
    if (tid < st) { red[tid] += red[tid + st]; red[256 + tid] += red[256 + tid + st]; }
    __syncthreads();
  }
  if (tid == 0) {
    atomicAdd(&out[b * 2 + 0], red[0]);
    atomicAdd(&out[b * 2 + 1], red[256]);
  }
}

extern "C" void kernel_launch(void* const* d_in, const int* in_sizes, int n_in,
                              void* d_out, int out_size, void* d_ws, size_t ws_size,
                              hipStream_t stream) {
  (void)in_sizes; (void)n_in; (void)out_size; (void)ws_size;
  const float* x          = (const float*)d_in[0];
  const float* qkv_w      = (const float*)d_in[1];
  const float* lae_proj_w = (const float*)d_in[2];
  const float* lae_proj_b = (const float*)d_in[3];
  const float* lq_w       = (const float*)d_in[4];
  const float* lkv_w      = (const float*)d_in[5];
  const float* lproj_w    = (const float*)d_in[6];
  const float* lproj_b    = (const float*)d_in[7];
  const float* cls_w      = (const float*)d_in[8];
  const float* cls_b      = (const float*)d_in[9];
  float* out = (float*)d_out;
  float* ws  = (float*)d_ws;

  float* xm   = ws + WS_XM;
  float* xs   = ws + WS_XS;
  float* qkvb = ws + WS_QKV;
  float* qb   = ws + WS_QB;
  float* kvb  = ws + WS_KVB;
  float* y    = ws + WS_Y;
  float* ga   = ws + WS_GA;

  k_mean_pool<<<196, 256, 0, stream>>>(x, cls_b, xm, xs, out);
  k_proj_in<<<198, 256, 0, stream>>>(xm, xs, qkv_w, lq_w, lkv_w, qkvb, qb, kvb);
  k_attn<<<800, 256, 0, stream>>>(qkvb, qb, kvb, y, ga);
  k_proj_cls<<<96, 256, 0, stream>>>(y, ga, lae_proj_w, lae_proj_b,
                                     lproj_w, lproj_b, cls_w, out);
}

// Round 12
// 127.476 us; speedup vs baseline: 1.1030x; 1.1030x over previous
//
#include <hip/hip_runtime.h>

// ===== Problem constants =====
// x: [28,14,14,256] -> mean over 7 -> xm[4,196,256]; avgpool2x2 -> xs[4,49,256]
// LAE: qkv = xm @ qkv_w^T [784,768]; per-pixel 3x3 dilated attn (d=1,3) -> y[784,256]
// GAE: q = xm @ lq_w^T [784,128]; kv = xs @ lkv_w^T [196,256]; attn -> ga[784,128]
// proj+cls fused: out[b,cls] = sum_p ((y@Wl^T+bl) . cwl + (ga@Wg^T+bg) . cwg) + cls_b
//
// Structure notes (measured, rounds 1-11):
//  - fixed harness overhead ~93us; minimal 4-dispatch chain ~37us => ~130us floor
//  - cooperative grid.sync costs ~60us/sync on 400 blocks -> never fuse via coop
//  - fusing the 7-group mean into the GEMM re-reads x 14x => +12us net loss
//  - full unroll of multi-load staging spills to scratch (1.2GB HBM traffic)
//  - 64x64 GEMM tiles REGRESSED +10us (latency regime: dur ~ per-block critical
//    path, grid fits in one wave; bigger tile = longer path). 32x64 is the point.

#define WS_XM    0           // 784*256  = 200704
#define WS_XS    200704      // 196*256  = 50176
#define WS_QKV   250880      // 784*768  = 602112
#define WS_QB    852992      // 784*128  = 100352
#define WS_KVB   953344      // 196*256  = 50176
#define WS_Y     1003520     // 784*256  = 200704
#define WS_GA    1204224     // 784*128  = 100352
// total floats = 1304576 (~5.2 MB)

// ---------- kernel 0: group-mean + 2x2 avg pool + out init ----------
// grid 196 = (b, 2x2-quad); 256 threads = 4 pixels x 64 float4-chunks.
__global__ __launch_bounds__(256) void k_mean_pool(const float* __restrict__ x,
                                                   const float* __restrict__ cls_b,
                                                   float* __restrict__ xm,
                                                   float* __restrict__ xs,
                                                   float* __restrict__ out) {
  __shared__ float4 sm[256];
  const int blk = blockIdx.x;
  const int b = blk / 49;
  const int q = blk % 49;
  const int ph2 = q / 7, pw2 = q % 7;
  const int tid = threadIdx.x;
  const int pix = tid >> 6;        // 0..3 -> (dy,dx)
  const int ch4 = (tid & 63) << 2; // float offset 0,4,...,252
  const int p = (ph2 * 2 + (pix >> 1)) * 14 + (pw2 * 2 + (pix & 1));

  const float* xp = x + ((size_t)(b * 1372 + p)) * 256 + ch4;
  float4 v = make_float4(0.f, 0.f, 0.f, 0.f);
  #pragma unroll
  for (int g = 0; g < 7; ++g) {
    const float4 t = *(const float4*)(xp + (size_t)g * 50176);
    v.x += t.x; v.y += t.y; v.z += t.z; v.w += t.w;
  }
  v.x *= (1.f/7.f); v.y *= (1.f/7.f); v.z *= (1.f/7.f); v.w *= (1.f/7.f);
  *(float4*)(xm + (size_t)(b * 196 + p) * 256 + ch4) = v;

  sm[tid] = v;
  __syncthreads();
  if (pix == 0) {
    const int c = tid & 63;
    const float4 v0 = sm[c], v1 = sm[64 + c], v2 = sm[128 + c], v3 = sm[192 + c];
    float4 s;
    s.x = (v0.x + v1.x + v2.x + v3.x) * 0.25f;
    s.y = (v0.y + v1.y + v2.y + v3.y) * 0.25f;
    s.z = (v0.z + v1.z + v2.z + v3.z) * 0.25f;
    s.w = (v0.w + v1.w + v2.w + v3.w) * 0.25f;
    *(float4*)(xs + (size_t)(b * 49 + q) * 256 + ch4) = s;
  }
  if (blk == 0 && tid < 8) out[tid] = cls_b[tid & 1];   // init classifier accumulators
}

// ---------- kernel 1: fused input projections ----------
// blocks 0..349:   [qkv|q] = xm @ [qkv_w;lq_w]^T  (M=784, N=896, K=256)
// blocks 350..377: kv = xs @ lkv_w^T              (M=196, N=256, K=256)
__global__ __launch_bounds__(256) void k_proj_in(const float* __restrict__ xm,
                                                 const float* __restrict__ xs,
                                                 const float* __restrict__ qkv_w,
                                                 const float* __restrict__ lq_w,
                                                 const float* __restrict__ lkv_w,
                                                 float* __restrict__ qkvb,
                                                 float* __restrict__ qb,
                                                 float* __restrict__ kvb) {
  __shared__ float As[32][68];
  __shared__ float Bs[64][68];
  const int tid = threadIdx.x;
  const int tx = tid & 15, ty = tid >> 4;
  const int bid = blockIdx.x;
  int region, mt, nt;
  if (bid < 350) { region = 0; mt = bid / 14; nt = bid % 14; }
  else { const int r = bid - 350; region = 1; mt = r / 4; nt = r % 4; }
  const float* A = region ? xs : xm;
  const int M = region ? 196 : 784;
  const int rowBase = mt * 32, colBase = nt * 64;

  float acc[2][4] = {{0.f,0.f,0.f,0.f},{0.f,0.f,0.f,0.f}};

  for (int kc = 0; kc < 256; kc += 64) {
    #pragma unroll
    for (int i = 0; i < 2; ++i) {
      const int e = tid + i * 256;
      const int r = e >> 4, k4 = (e & 15) << 2;
      const int row = rowBase + r;
      float4 v = make_float4(0.f, 0.f, 0.f, 0.f);
      if (row < M) v = *(const float4*)(A + (size_t)row * 256 + kc + k4);
      *(float4*)(&As[r][k4]) = v;
    }
    #pragma unroll
    for (int i = 0; i < 4; ++i) {
      const int e = tid + i * 256;
      const int n = e >> 4, k4 = (e & 15) << 2;
      const int col = colBase + n;
      const float* Wp; int wr;
      if (region == 1)      { Wp = lkv_w; wr = col; }
      else if (col < 768)   { Wp = qkv_w; wr = col; }
      else                  { Wp = lq_w;  wr = col - 768; }
      *(float4*)(&Bs[n][k4]) = *(const float4*)(Wp + (size_t)wr * 256 + kc + k4);
    }
    __syncthreads();
    #pragma unroll
    for (int k = 0; k < 64; k += 4) {
      const float4 a0 = *(const float4*)(&As[ty][k]);
      const float4 a1 = *(const float4*)(&As[ty + 16][k]);
      const float4 c0 = *(const float4*)(&Bs[tx][k]);
      const float4 c1 = *(const float4*)(&Bs[tx + 16][k]);
      const float4 c2 = *(const float4*)(&Bs[tx + 32][k]);
      const float4 c3 = *(const float4*)(&Bs[tx + 48][k]);
      acc[0][0] += a0.x*c0.x + a0.y*c0.y + a0.z*c0.z + a0.w*c0.w;
      acc[0][1] += a0.x*c1.x + a0.y*c1.y + a0.z*c1.z + a0.w*c1.w;
      acc[0][2] += a0.x*c2.x + a0.y*c2.y + a0.z*c2.z + a0.w*c2.w;
      acc[0][3] += a0.x*c3.x + a0.y*c3.y + a0.z*c3.z + a0.w*c3.w;
      acc[1][0] += a1.x*c0.x + a1.y*c0.y + a1.z*c0.z + a1.w*c0.w;
      acc[1][1] += a1.x*c1.x + a1.y*c1.y + a1.z*c1.z + a1.w*c1.w;
      acc[1][2] += a1.x*c2.x + a1.y*c2.y + a1.z*c2.z + a1.w*c2.w;
      acc[1][3] += a1.x*c3.x + a1.y*c3.y + a1.z*c3.z + a1.w*c3.w;
    }
    __syncthreads();
  }

  #pragma unroll
  for (int j = 0; j < 4; ++j) {
    const int col = colBase + tx + 16 * j;
    #pragma unroll
    for (int i = 0; i < 2; ++i) {
      const int row = rowBase + ty + 16 * i;
      if (row >= M) continue;
      if (region == 1)    kvb[(size_t)row * 256 + col] = acc[i][j];
      else if (col < 768) qkvb[(size_t)row * 768 + col] = acc[i][j];
      else                qb[(size_t)row * 128 + col - 768] = acc[i][j];
    }
  }
}

// ---------- kernel 2: attention (LAE blocks 0..783, GAE blocks 784..799) ----------
__global__ __launch_bounds__(256) void k_attn(const float* __restrict__ qkvb,
                                              const float* __restrict__ qb,
                                              const float* __restrict__ kvb,
                                              float* __restrict__ y,
                                              float* __restrict__ ga) {
  __shared__ float Ks[49 * 32];
  __shared__ float Vs[49 * 32];
  const int bid = blockIdx.x;
  const int tid = threadIdx.x;

  if (bid < 784) {
    // ---- LAE per-pixel dilated 3x3 window attention ----
    const int b = bid / 196, p = bid % 196;
    const int ph = p / 14, pw = p % 14;
    const int c = tid;
    const int d = (c < 128) ? 1 : 3;
    const float qv = qkvb[(size_t)bid * 768 + c];
    float s[9];
    #pragma unroll
    for (int j = 0; j < 9; ++j) {
      const int nh = ph + (j / 3 - 1) * d;
      const int nw = pw + (j % 3 - 1) * d;
      float kval = 0.f;
      if ((unsigned)nh < 14u && (unsigned)nw < 14u)
        kval = qkvb[((size_t)(b * 196 + nh * 14 + nw)) * 768 + 256 + c];
      float t = qv * kval;
      t += __shfl_xor(t, 1);
      t += __shfl_xor(t, 2);
      t += __shfl_xor(t, 4);
      t += __shfl_xor(t, 8);
      t += __shfl_xor(t, 16);
      s[j] = t * 0.17677669529663687f;   // 32^-0.5
    }
    float mx = s[0];
    #pragma unroll
    for (int j = 1; j < 9; ++j) mx = fmaxf(mx, s[j]);
    float sum = 0.f;
    #pragma unroll
    for (int j = 0; j < 9; ++j) { s[j] = __expf(s[j] - mx); sum += s[j]; }
    const float inv = 1.f / sum;
    float o = 0.f;
    #pragma unroll
    for (int j = 0; j < 9; ++j) {
      const int nh = ph + (j / 3 - 1) * d;
      const int nw = pw + (j % 3 - 1) * d;
      if ((unsigned)nh < 14u && (unsigned)nw < 14u)
        o += s[j] * qkvb[((size_t)(b * 196 + nh * 14 + nw)) * 768 + 512 + c];
    }
    y[(size_t)bid * 256 + c] = o * inv;
  } else {
    // ---- GAE attention: 196 queries x 49 keys per (b,head) ----
    const int g = bid - 784;
    const int b = g >> 2, h = g & 3;
    for (int e = tid; e < 49 * 32; e += 256) {
      const int kk = e >> 5, cc = e & 31;
      Ks[e] = kvb[(size_t)(b * 49 + kk) * 256 + h * 32 + cc];
      Vs[e] = kvb[(size_t)(b * 49 + kk) * 256 + 128 + h * 32 + cc];
    }
    __syncthreads();
    if (tid < 196) {
      float q[32], o[32];
      #pragma unroll
      for (int cc = 0; cc < 32; ++cc) {
        q[cc] = qb[(size_t)(b * 196 + tid) * 128 + h * 32 + cc];
        o[cc] = 0.f;
      }
      float m = -1e30f, l = 0.f;
      for (int kk = 0; kk < 49; ++kk) {
        float sc = 0.f;
        #pragma unroll
        for (int cc = 0; cc < 32; ++cc) sc += q[cc] * Ks[kk * 32 + cc];
        sc *= 0.177f;                  // SCALE_GAE (hard-coded in reference)
        if (sc > m) {
          const float r = __expf(m - sc);
          l *= r;
          #pragma unroll
          for (int cc = 0; cc < 32; ++cc) o[cc] *= r;
          m = sc;
        }
        const float pch = __expf(sc - m);
        l += pch;
        #pragma unroll
        for (int cc = 0; cc < 32; ++cc) o[cc] += pch * Vs[kk * 32 + cc];
      }
      const float inv = 1.f / l;
      #pragma unroll
      for (int cc = 0; cc < 32; ++cc)
        ga[(size_t)(b * 196 + tid) * 128 + h * 32 + cc] = o[cc] * inv;
    }
  }
}

// ---------- kernel 3: output projections + classifier ----------
// blocks 0..111:  lae tile = y_b @ lae_proj_w^T + b  (per-b, 7 ptiles x 4 ntiles)
// blocks 112..167: gae tile = ga_b @ lproj_w^T + b   (per-b, 7 ptiles x 2 ntiles)
__global__ __launch_bounds__(256) void k_proj_cls(const float* __restrict__ y,
                                                  const float* __restrict__ ga,
                                                  const float* __restrict__ lae_w,
                                                  const float* __restrict__ lae_b,
                                                  const float* __restrict__ lproj_w,
                                                  const float* __restrict__ lproj_b,
                                                  const float* __restrict__ cw,
                                                  float* __restrict__ out) {
  __shared__ float As[32][68];
  __shared__ float Bs[64][68];
  const int tid = threadIdx.x;
  const int tx = tid & 15, ty = tid >> 4;
  const int bid = blockIdx.x;
  int region, b, pt, nt;
  if (bid < 112) { region = 0; b = bid / 28; const int r = bid % 28; pt = r / 4; nt = r % 4; }
  else { const int q = bid - 112; region = 1; b = q / 14; const int r = q % 14; pt = r / 2; nt = r % 2; }

  const float* A; const float* W; const float* bias;
  int lda, K, colOff;
  if (region == 0) { A = y  + (size_t)b * 196 * 256; lda = 256; K = 256; W = lae_w;   bias = lae_b;   colOff = 0; }
  else             { A = ga + (size_t)b * 196 * 128; lda = 128; K = 128; W = lproj_w; bias = lproj_b; colOff = 256; }
  const int colBase = nt * 64;

  float acc[2][4] = {{0.f,0.f,0.f,0.f},{0.f,0.f,0.f,0.f}};

  for (int kc = 0; kc < K; kc += 64) {
    #pragma unroll
    for (int i = 0; i < 2; ++i) {
      const int e = tid + i * 256;
      const int r = e >> 4, k4 = (e & 15) << 2;
      const int p = pt * 32 + r;
      float4 v = make_float4(0.f, 0.f, 0.f, 0.f);
      if (p < 196) v = *(const float4*)(A + (size_t)p * lda + kc + k4);
      *(float4*)(&As[r][k4]) = v;
    }
    #pragma unroll
    for (int i = 0; i < 4; ++i) {
      const int e = tid + i * 256;
      const int n = e >> 4, k4 = (e & 15) << 2;
      const int col = colBase + n;
      *(float4*)(&Bs[n][k4]) = *(const float4*)(W + (size_t)col * K + kc + k4);
    }
    __syncthreads();
    #pragma unroll
    for (int k = 0; k < 64; k += 4) {
      const float4 a0 = *(const float4*)(&As[ty][k]);
      const float4 a1 = *(const float4*)(&As[ty + 16][k]);
      const float4 c0 = *(const float4*)(&Bs[tx][k]);
      const float4 c1 = *(const float4*)(&Bs[tx + 16][k]);
      const float4 c2 = *(const float4*)(&Bs[tx + 32][k]);
      const float4 c3 = *(const float4*)(&Bs[tx + 48][k]);
      acc[0][0] += a0.x*c0.x + a0.y*c0.y + a0.z*c0.z + a0.w*c0.w;
      acc[0][1] += a0.x*c1.x + a0.y*c1.y + a0.z*c1.z + a0.w*c1.w;
      acc[0][2] += a0.x*c2.x + a0.y*c2.y + a0.z*c2.z + a0.w*c2.w;
      acc[0][3] += a0.x*c3.x + a0.y*c3.y + a0.z*c3.z + a0.w*c3.w;
      acc[1][0] += a1.x*c0.x + a1.y*c0.y + a1.z*c0.z + a1.w*c0.w;
      acc[1][1] += a1.x*c1.x + a1.y*c1.y + a1.z*c1.z + a1.w*c1.w;
      acc[1][2] += a1.x*c2.x + a1.y*c2.y + a1.z*c2.z + a1.w*c2.w;
      acc[1][3] += a1.x*c3.x + a1.y*c3.y + a1.z*c3.z + a1.w*c3.w;
    }
    __syncthreads();
  }

  float s0 = 0.f, s1 = 0.f;
  #pragma unroll
  for (int j = 0; j < 4; ++j) {
    const int col = colBase + tx + 16 * j;
    const float bv = bias[col];
    #pragma unroll
    for (int i = 0; i < 2; ++i) {
      const int p = pt * 32 + ty + 16 * i;
      if (p >= 196) continue;
      const float v = acc[i][j] + bv;
      const size_t fidx = (size_t)p * 384 + colOff + col;
      s0 += v * cw[fidx];
      s1 += v * cw[75264 + fidx];
    }
  }
  float* red = &As[0][0];          // reuse LDS (loop ended with __syncthreads)
  red[tid] = s0;
  red[256 + tid] = s1;
  __syncthreads();
  for (int st = 128; st > 0; st >>= 1) {
    if (tid < st) { red[tid] += red[tid + st]; red[256 + tid] += red[256 + tid + st]; }
    __syncthreads();
  }
  if (tid == 0) {
    atomicAdd(&out[b * 2 + 0], red[0]);
    atomicAdd(&out[b * 2 + 1], red[256]);
  }
}

extern "C" void kernel_launch(void* const* d_in, const int* in_sizes, int n_in,
                              void* d_out, int out_size, void* d_ws, size_t ws_size,
                              hipStream_t stream) {
  (void)in_sizes; (void)n_in; (void)out_size; (void)ws_size;
  const float* x          = (const float*)d_in[0];
  const float* qkv_w      = (const float*)d_in[1];
  const float* lae_proj_w = (const float*)d_in[2];
  const float* lae_proj_b = (const float*)d_in[3];
  const float* lq_w       = (const float*)d_in[4];
  const float* lkv_w      = (const float*)d_in[5];
  const float* lproj_w    = (const float*)d_in[6];
  const float* lproj_b    = (const float*)d_in[7];
  const float* cls_w      = (const float*)d_in[8];
  const float* cls_b      = (const float*)d_in[9];
  float* out = (float*)d_out;
  float* ws  = (float*)d_ws;

  float* xm   = ws + WS_XM;
  float* xs   = ws + WS_XS;
  float* qkvb = ws + WS_QKV;
  float* qb   = ws + WS_QB;
  float* kvb  = ws + WS_KVB;
  float* y    = ws + WS_Y;
  float* ga   = ws + WS_GA;

  k_mean_pool<<<196, 256, 0, stream>>>(x, cls_b, xm, xs, out);
  k_proj_in<<<378, 256, 0, stream>>>(xm, xs, qkv_w, lq_w, lkv_w, qkvb, qb, kvb);
  k_attn<<<800, 256, 0, stream>>>(qkvb, qb, kvb, y, ga);
  k_proj_cls<<<168, 256, 0, stream>>>(y, ga, lae_proj_w, lae_proj_b,
                                      lproj_w, lproj_b, cls_w, out);
}